// Round 19
// baseline (119.794 us; speedup 1.0000x reference)
//
#include <hip/hip_runtime.h>
#include <hip/hip_fp16.h>

constexpr int N_NODES = 100000;
constexpr int E_EDGES = 3200000;
constexpr int F_IN    = 256;
constexpr int HID     = 32;
constexpr int NCLS    = 10;

// bucketing: bucket = col >> 7  (128 target nodes per bucket)
constexpr int BUCK_SHIFT = 7;
constexpr int NPB        = 128;                          // nodes per bucket
constexpr int NBUCK      = (N_NODES + NPB - 1) / NPB;    // 782
constexpr int EPB        = 8192;                         // edges per scat block
constexpr int NBLK1      = (E_EDGES + EPB - 1) / EPB;    // 391
constexpr int CAP        = 6144;   // fixed bucket capacity (mean 4092, sigma 64)

// ---------------- ws layout (byte offsets) ----------------
constexpr size_t OFF_FLAG = 0;
constexpr size_t OFF_GCUR = 4u << 10;    // 782 ints
constexpr size_t OFF_W1F  = 32u << 10;   // 16 KB fragment-ordered bf16 W1
constexpr size_t OFF_CNT  = 1u << 20;
constexpr size_t OFF_OFF  = 3u << 20;
constexpr size_t OFF_DINV = 4u << 20;
constexpr size_t OFF_CSR  = 5u << 20;    // sparse, 782*6144*4 = 19.2 MB -> ends 24.2MB
constexpr size_t OFF_BIN  = 25u << 20;   // sparse, 19.2 MB -> ends 44.2MB
constexpr size_t OFF_HS   = 25u << 20;   // fp16 h*dinv, overlays binned after k_p2

typedef __attribute__((ext_vector_type(8))) short bf16x8;
typedef __attribute__((ext_vector_type(4))) float f32x4;

// bf16 helpers (RNE) -- used for the MFMA W1/A fragments only
__device__ __forceinline__ unsigned pack_bf16x2(float a, float b) {
    unsigned ua = __float_as_uint(a), ub = __float_as_uint(b);
    ua = (ua + 0x7FFFu + ((ua >> 16) & 1u)) >> 16;
    ub = (ub + 0x7FFFu + ((ub >> 16) & 1u)) >> 16;
    return ua | (ub << 16);
}
__device__ __forceinline__ __half2 u2h(unsigned u) {
    union { unsigned u; __half2 h; } v; v.u = u; return v.h;
}

__device__ __forceinline__ int load_idx(const void* ei, long long i, int is64) {
    if (is64) return (int)((const long long*)ei)[i];
    return ((const int*)ei)[i];
}

// ---------------------------------------------------------------------------
// init: dtype detect + gcur init + W1 -> bf16 MFMA B-fragment layout.
// ---------------------------------------------------------------------------
__global__ __launch_bounds__(1024) void k_initw(const int* __restrict__ ei32,
                                                int* __restrict__ flag,
                                                int* __restrict__ gcur,
                                                const float* __restrict__ W1,
                                                unsigned* __restrict__ w1f) {
    __shared__ int nz;
    int tid = threadIdx.x;
    if (tid == 0) nz = 0;
    __syncthreads();
    if (ei32[2 * tid + 1] != 0) atomicOr(&nz, 1);
    __syncthreads();
    if (tid == 0) flag[0] = (nz == 0) ? 1 : 0;   // 1 => int64 storage
    if (tid < NBUCK) gcur[tid] = tid * CAP;

    #pragma unroll
    for (int q = 0; q < 4; q++) {
        int i = tid + q * 1024;                  // 4096 u32 entries
        int p    = i & 3;
        int lane = (i >> 2) & 63;
        int f    = i >> 8;
        int ks = f >> 1, t = f & 1;
        int kg = lane >> 4, col = lane & 15;
        int k0 = ks * 32 + kg * 8 + p * 2;
        float w0 = W1[k0 * HID + t * 16 + col];
        float w1 = W1[(k0 + 1) * HID + t * 16 + col];
        w1f[i] = pack_bf16x2(w0, w1);
    }
}

// ---------------------------------------------------------------------------
// ONE-PASS bucketed scatter. Round 18->19: REGISTER staging (8 edges/thread
// in VGPRs; was 48 KB LDS sval/sbuck). LDS drops to 6.3 KB -> occupancy cap
// 2 -> 8 blocks/CU; LDS traffic -75% (only the hist/cursor atomics remain).
// ---------------------------------------------------------------------------
__global__ __launch_bounds__(1024) void k_scat(const void* __restrict__ ei,
                                               const int* __restrict__ flag,
                                               int* __restrict__ gcur,
                                               unsigned* __restrict__ binned) {
    __shared__ int h[NBUCK];                 // 3.1 KB
    __shared__ int cur[NBUCK];               // 3.1 KB
    int tid = threadIdx.x, blk = blockIdx.x;
    for (int i = tid; i < NBUCK; i += 1024) h[i] = 0;
    __syncthreads();

    int is64 = flag[0];
    int base = blk * EPB;
    int nedge = min(EPB, E_EDGES - base);

    unsigned val[8];
    int      bk[8];
    #pragma unroll
    for (int j = 0; j < 8; j++) {
        int k = tid + j * 1024;
        if (k < nedge) {
            int i = base + k;
            int r = load_idx(ei, i, is64);
            int c = load_idx(ei, (long long)E_EDGES + i, is64);
            bk[j]  = c >> BUCK_SHIFT;
            val[j] = ((unsigned)r << BUCK_SHIFT) | ((unsigned)c & (NPB - 1));
            atomicAdd(&h[bk[j]], 1);
        } else {
            bk[j] = -1;
        }
    }
    __syncthreads();

    for (int j = tid; j < NBUCK; j += 1024) {
        int c = h[j];
        cur[j] = (c > 0) ? atomicAdd(&gcur[j], c) : 0;
    }
    __syncthreads();

    #pragma unroll
    for (int j = 0; j < 8; j++) {
        if (bk[j] >= 0) {
            int d = atomicAdd(&cur[bk[j]], 1);
            binned[d] = val[j];
        }
    }
}

// ---------------------------------------------------------------------------
// pass 2: stage segment in LDS once, counting-sort to SPARSE csr at b*CAP.
// Emits cnt/off/dinv. 1024 threads.
// ---------------------------------------------------------------------------
__global__ __launch_bounds__(1024) void k_p2(const unsigned* __restrict__ binned,
                                             const int* __restrict__ gcur,
                                             int* __restrict__ cnt,
                                             int* __restrict__ off,
                                             float* __restrict__ dinv,
                                             int* __restrict__ csr) {
    __shared__ unsigned sval[CAP];           // 24.6 KB staged segment
    __shared__ int lcnt[NPB], sc[NPB], lcur[NPB];
    int b = blockIdx.x, tid = threadIdx.x;
    int s = b * CAP;
    int m = gcur[b] - s;                     // entries in this bucket
    if (tid < NPB) lcnt[tid] = 0;
    __syncthreads();
    for (int i = tid; i < m; i += 1024) {
        unsigned p = binned[s + i];
        sval[i] = p;
        atomicAdd(&lcnt[p & (NPB - 1)], 1);
    }
    __syncthreads();
    if (tid < NPB) sc[tid] = lcnt[tid];
    __syncthreads();
    for (int d = 1; d < NPB; d <<= 1) {
        int t = 0;
        if (tid < NPB && tid >= d) t = sc[tid - d];
        __syncthreads();
        if (tid < NPB) sc[tid] += t;
        __syncthreads();
    }
    if (tid < NPB) {
        int o = s + sc[tid] - lcnt[tid];     // sparse exclusive position
        lcur[tid] = o;
        int node = b * NPB + tid;
        if (node < N_NODES) {
            off[node]  = o;
            cnt[node]  = lcnt[tid];
            dinv[node] = rsqrtf((float)lcnt[tid] + 1.0f);   // +1 self-loop
        }
    }
    __syncthreads();
    for (int i = tid; i < m; i += 1024) {
        unsigned p = sval[i];
        int pos = atomicAdd(&lcur[p & (NPB - 1)], 1);
        csr[pos] = (int)(p >> BUCK_SHIFT);
    }
}

// ---------------------------------------------------------------------------
// h = feature @ W1 via MFMA bf16; hs = FP16(h * dinv_row), ushort [node][32].
// One wave per 16-node batch; no LDS.
// ---------------------------------------------------------------------------
__global__ __launch_bounds__(256) void k_h(const float* __restrict__ feat,
                                           const unsigned* __restrict__ w1f,
                                           const float* __restrict__ dinv,
                                           unsigned short* __restrict__ hs16s) {
    int tid  = threadIdx.x;
    int lane = tid & 63;
    long wid = (long)blockIdx.x * 4 + (tid >> 6);
    int n0 = (int)(wid * 16);
    if (n0 >= N_NODES) return;

    bf16x8 bfrag[16];
    const bf16x8* wv = (const bf16x8*)w1f;
    #pragma unroll
    for (int f = 0; f < 16; f++) bfrag[f] = wv[f * 64 + lane];

    int arow = lane & 15;
    int kg   = lane >> 4;
    const float4* fr = (const float4*)(feat + (size_t)(n0 + arow) * F_IN);

    f32x4 acc0 = {0.f, 0.f, 0.f, 0.f};
    f32x4 acc1 = {0.f, 0.f, 0.f, 0.f};

    #pragma unroll
    for (int ks = 0; ks < 8; ks++) {
        float4 fa = fr[ks * 8 + kg * 2 + 0];
        float4 fb = fr[ks * 8 + kg * 2 + 1];
        unsigned au[4];
        au[0] = pack_bf16x2(fa.x, fa.y);
        au[1] = pack_bf16x2(fa.z, fa.w);
        au[2] = pack_bf16x2(fb.x, fb.y);
        au[3] = pack_bf16x2(fb.z, fb.w);
        bf16x8 af = *(bf16x8*)au;
        acc0 = __builtin_amdgcn_mfma_f32_16x16x32_bf16(af, bfrag[ks * 2 + 0], acc0, 0, 0, 0);
        acc1 = __builtin_amdgcn_mfma_f32_16x16x32_bf16(af, bfrag[ks * 2 + 1], acc1, 0, 0, 0);
    }

    int rb = kg * 4;
    #pragma unroll
    for (int r = 0; r < 4; r++) {
        int node = n0 + rb + r;
        float di = dinv[node];
        hs16s[(size_t)node * HID + arow]      = __half_as_ushort(__float2half(acc0[r] * di));
        hs16s[(size_t)node * HID + 16 + arow] = __half_as_ushort(__float2half(acc1[r] * di));
    }
}

// ---------------------------------------------------------------------------
// FUSED agg + relu + W2 matvec + log_softmax. fp16 hs + packed v_pk_add_f16,
// 8-deep unroll, 4 lanes per node; 64 nodes per block.
// ---------------------------------------------------------------------------
__global__ __launch_bounds__(256) void k_aggout(const int* __restrict__ off,
                                                const int* __restrict__ cnt,
                                                const int* __restrict__ csr,
                                                const unsigned* __restrict__ hs16,
                                                const float* __restrict__ dinv,
                                                const float* __restrict__ b1,
                                                const float* __restrict__ W2,
                                                const float* __restrict__ b2,
                                                float* __restrict__ out) {
    __shared__ float W2s[HID * NCLS];   // [k][c]
    __shared__ float b2s[NCLS];
    int tid = threadIdx.x;
    for (int i = tid; i < HID * NCLS; i += 256) W2s[i] = W2[i];
    if (tid < NCLS) b2s[tid] = b2[tid];
    __syncthreads();

    int l2   = tid & 3;                  // quarter-row: hid 8*l2 .. 8*l2+7
    int g    = tid >> 2;                 // 0..63
    int node = blockIdx.x * 64 + g;
    if (node >= N_NODES) return;

    int o = off[node];
    int n = cnt[node];

    const uint4* hsv = (const uint4*)hs16;     // row = 4 uint4
    uint4 ps = hsv[(size_t)node * 4 + l2];     // self-loop term
    __half2 s0 = u2h(ps.x), s1 = u2h(ps.y), s2 = u2h(ps.z), s3 = u2h(ps.w);

    #define ADDQ(Q) \
        s0 = __hadd2(s0, u2h(Q.x)); s1 = __hadd2(s1, u2h(Q.y)); \
        s2 = __hadd2(s2, u2h(Q.z)); s3 = __hadd2(s3, u2h(Q.w));

    int i = 0;
    for (; i + 8 <= n; i += 8) {
        int r0 = csr[o + i + 0];
        int r1 = csr[o + i + 1];
        int r2 = csr[o + i + 2];
        int r3 = csr[o + i + 3];
        int r4 = csr[o + i + 4];
        int r5 = csr[o + i + 5];
        int r6 = csr[o + i + 6];
        int r7 = csr[o + i + 7];
        uint4 q0 = hsv[(size_t)r0 * 4 + l2];
        uint4 q1 = hsv[(size_t)r1 * 4 + l2];
        uint4 q2 = hsv[(size_t)r2 * 4 + l2];
        uint4 q3 = hsv[(size_t)r3 * 4 + l2];
        uint4 q4 = hsv[(size_t)r4 * 4 + l2];
        uint4 q5 = hsv[(size_t)r5 * 4 + l2];
        uint4 q6 = hsv[(size_t)r6 * 4 + l2];
        uint4 q7 = hsv[(size_t)r7 * 4 + l2];
        ADDQ(q0) ADDQ(q1) ADDQ(q2) ADDQ(q3)
        ADDQ(q4) ADDQ(q5) ADDQ(q6) ADDQ(q7)
    }
    for (; i < n; i++) {
        uint4 q = hsv[(size_t)csr[o + i] * 4 + l2];
        ADDQ(q)
    }
    #undef ADDQ

    float2 f0 = __half22float2(s0);
    float2 f1 = __half22float2(s1);
    float2 f2 = __half22float2(s2);
    float2 f3 = __half22float2(s3);

    float di = dinv[node];
    float4 b1lo = *(const float4*)(b1 + 8 * l2);
    float4 b1hi = *(const float4*)(b1 + 8 * l2 + 4);
    float act[8];
    act[0] = fmaxf(b1lo.x + f0.x * di, 0.f);
    act[1] = fmaxf(b1lo.y + f0.y * di, 0.f);
    act[2] = fmaxf(b1lo.z + f1.x * di, 0.f);
    act[3] = fmaxf(b1lo.w + f1.y * di, 0.f);
    act[4] = fmaxf(b1hi.x + f2.x * di, 0.f);
    act[5] = fmaxf(b1hi.y + f2.y * di, 0.f);
    act[6] = fmaxf(b1hi.z + f3.x * di, 0.f);
    act[7] = fmaxf(b1hi.w + f3.y * di, 0.f);

    float p[NCLS];
    #pragma unroll
    for (int c = 0; c < NCLS; c++) {
        float s = 0.f;
        #pragma unroll
        for (int k = 0; k < 8; k++) s = fmaf(act[k], W2s[(8 * l2 + k) * NCLS + c], s);
        p[c] = s;
    }

    #pragma unroll
    for (int d = 1; d < 4; d <<= 1) {
        #pragma unroll
        for (int c = 0; c < NCLS; c++) p[c] += __shfl_xor(p[c], d, 4);
    }

    #pragma unroll
    for (int c = 0; c < NCLS; c++) p[c] += b2s[c];
    float m = p[0];
    #pragma unroll
    for (int c = 1; c < NCLS; c++) m = fmaxf(m, p[c]);
    float se = 0.f;
    #pragma unroll
    for (int c = 0; c < NCLS; c++) se += expf(p[c] - m);
    float lse = m + logf(se);

    #pragma unroll
    for (int q = 0; q < 3; q++) {
        int c = l2 + 4 * q;
        if (c < NCLS) {
            float v = p[0];
            #pragma unroll
            for (int cc = 1; cc < NCLS; cc++) v = (c == cc) ? p[cc] : v;
            out[(size_t)node * NCLS + c] = v - lse;
        }
    }
}

// ---------------------------------------------------------------------------
extern "C" void kernel_launch(void* const* d_in, const int* in_sizes, int n_in,
                              void* d_out, int out_size, void* d_ws, size_t ws_size,
                              hipStream_t stream) {
    const float* feat = (const float*)d_in[0];
    const void*  ei   = d_in[1];
    const float* W1   = (const float*)d_in[2];
    const float* b1   = (const float*)d_in[3];
    const float* W2   = (const float*)d_in[4];
    const float* b2   = (const float*)d_in[5];
    float* out = (float*)d_out;

    char* ws = (char*)d_ws;
    int*      flag   = (int*)(ws + OFF_FLAG);
    int*      gcur   = (int*)(ws + OFF_GCUR);
    unsigned* w1f    = (unsigned*)(ws + OFF_W1F);
    int*      cnt    = (int*)(ws + OFF_CNT);
    int*      off    = (int*)(ws + OFF_OFF);
    float*    dinv   = (float*)(ws + OFF_DINV);
    int*      csr    = (int*)(ws + OFF_CSR);
    unsigned* binned = (unsigned*)(ws + OFF_BIN);
    unsigned* hs16   = (unsigned*)(ws + OFF_HS);   // overlays binned after k_p2

    k_initw<<<1, 1024, 0, stream>>>((const int*)ei, flag, gcur, W1, w1f);
    k_scat<<<NBLK1, 1024, 0, stream>>>(ei, flag, gcur, binned);
    k_p2<<<NBUCK, 1024, 0, stream>>>(binned, gcur, cnt, off, dinv, csr);

    k_h<<<(N_NODES / 16 + 3) / 4, 256, 0, stream>>>(feat, w1f, dinv,
                                                    (unsigned short*)hs16);
    k_aggout<<<(N_NODES + 63) / 64, 256, 0, stream>>>(off, cnt, csr, hs16, dinv,
                                                      b1, W2, b2, out);
}